// Round 20
// baseline (83.595 us; speedup 1.0000x reference)
//
#include <hip/hip_runtime.h>
#include <hip/hip_bf16.h>

typedef __attribute__((ext_vector_type(8))) short short8;
typedef __attribute__((ext_vector_type(16))) float f32x16;
typedef __attribute__((ext_vector_type(4))) float f32x4n;  // native vec for nt-store

__device__ __forceinline__ unsigned short bfbits(float f) {
  return __builtin_bit_cast(unsigned short, __float2bfloat16(f));
}

__device__ __forceinline__ short8 lds_read16(const short* p, int byteOff) {
  return *reinterpret_cast<const short8*>(reinterpret_cast<const char*>(p) + byteOff);
}

#define MFMA(a, b, c) __builtin_amdgcn_mfma_f32_32x32x16_bf16((a), (b), (c), 0, 0, 0)

// x:[524288][64] f32, w1:[8][64][256] f32, w2:[8][256][64] f32, out = x shape.
// Grid 512 x 768 threads. expert = blockIdx&7 (XCD-pinned), chunk =
// blockIdx>>3 in 0..63 owns 1024 rows = 32 tiles of 32 rows.
// Tile split across 12 waves: wv<8 -> 3 tiles, wv>=8 -> 2 tiles.
//
// R20 = R19 with the nt-store compile fix (native ext_vector float4; HIP's
// float4 class is rejected by __builtin_nontemporal_store).
// THEORY (untested R19): FETCH=67MB = half of x misses L3 each pass because
// 134 MB of write-once output streams through L3 evicting x. nt stores keep
// L3 for x -> HBM reads collapse; removes read-congestion from the x loads.
//
// R18 (kept): exchange-free GEMM2 via f-permutation -- W2 chunk (ks2,g2)
// holds physical rows 16ks2+4g2+{0..3},16ks2+8+4g2+{0..3} so the lane's own
// pk quads ARE the B-fragment (no shfl_xor network).
//
// Measured trail: R11 16w=67.5 -> R15 24w=65.8 -> R18 exch-free=64.5us.
// All pipes <=27%; latency-plateau at 2.05x the 31.4us HBM floor.
// LDS layouts (R13): conflict-free, addr=base+imm:
//   w1t chunk(c=ks*2+g, f):  byte c*4096 + f*16 = W1^T[f][d=8c..8c+7]
//   w2t chunk(c2=ks2*2+g,d): byte c2*1024 + d*16 (permuted contents above)
__launch_bounds__(768, 2)
__global__ void ffn_fused(const float* __restrict__ x,
                          const float* __restrict__ w1,
                          const float* __restrict__ w2,
                          float* __restrict__ out) {
  __shared__ short w1t[4 * 2 * 256 * 8];   // 32 KB
  __shared__ short w2t[16 * 2 * 64 * 8];   // 32 KB

  const int tid  = threadIdx.x;
  const int lane = tid & 63;
  const int wv   = tid >> 6;   // wave 0..11
  const int m    = lane & 31;
  const int g    = lane >> 5;

  const int e     = blockIdx.x & 7;   // expert -> XCD pinned (weights L2-hot)
  const int chunk = blockIdx.x >> 3;  // 0..63

  const float* W1 = w1 + e * (64 * 256);
  const float* W2 = w2 + e * (256 * 64);

  // ---- stage W1 chunks (threads 0..511 only) ----
  if (tid < 512) {
    const int f  = tid & 255;
    const int cb = (tid >> 8) * 4;
#pragma unroll 2
    for (int ci = 0; ci < 4; ++ci) {
      const int c  = cb + ci;     // c = ks*2+g
      const int d0 = c * 8;
      unsigned u0, u1, u2, u3;
      {
        float a0 = W1[(d0 + 0) * 256 + f], a1 = W1[(d0 + 1) * 256 + f];
        float a2 = W1[(d0 + 2) * 256 + f], a3 = W1[(d0 + 3) * 256 + f];
        float a4 = W1[(d0 + 4) * 256 + f], a5 = W1[(d0 + 5) * 256 + f];
        float a6 = W1[(d0 + 6) * 256 + f], a7 = W1[(d0 + 7) * 256 + f];
        u0 = (unsigned)bfbits(a0) | ((unsigned)bfbits(a1) << 16);
        u1 = (unsigned)bfbits(a2) | ((unsigned)bfbits(a3) << 16);
        u2 = (unsigned)bfbits(a4) | ((unsigned)bfbits(a5) << 16);
        u3 = (unsigned)bfbits(a6) | ((unsigned)bfbits(a7) << 16);
      }
      *reinterpret_cast<uint4*>(reinterpret_cast<char*>(w1t) + c * 4096 + f * 16) =
          make_uint4(u0, u1, u2, u3);
    }
  }
  // ---- stage W2 chunks (f-PERMUTED): chunk c2 = ks2*2 + g2 holds physical
  //      rows 16ks2+4g2+{0..3} then 16ks2+8+4g2+{0..3} ----
  {
    const int d = tid & 63;
    const int r = tid >> 6;
#pragma unroll 1
    for (int ci = 0; ci < 3; ++ci) {
      const int c2 = r + 12 * ci;  // r<8: 3 chunks; r>=8: 2 chunks
      if (c2 < 32) {
        const int g2    = c2 & 1;
        const int ks2   = c2 >> 1;
        const int fbase = 16 * ks2 + 4 * g2;
        unsigned u0, u1, u2, u3;
        {
          float a0 = W2[(fbase + 0) * 64 + d], a1 = W2[(fbase + 1) * 64 + d];
          float a2 = W2[(fbase + 2) * 64 + d], a3 = W2[(fbase + 3) * 64 + d];
          float a4 = W2[(fbase + 8) * 64 + d], a5 = W2[(fbase + 9) * 64 + d];
          float a6 = W2[(fbase + 10) * 64 + d], a7 = W2[(fbase + 11) * 64 + d];
          u0 = (unsigned)bfbits(a0) | ((unsigned)bfbits(a1) << 16);
          u1 = (unsigned)bfbits(a2) | ((unsigned)bfbits(a3) << 16);
          u2 = (unsigned)bfbits(a4) | ((unsigned)bfbits(a5) << 16);
          u3 = (unsigned)bfbits(a6) | ((unsigned)bfbits(a7) << 16);
        }
        *reinterpret_cast<uint4*>(reinterpret_cast<char*>(w2t) + c2 * 1024 + d * 16) =
            make_uint4(u0, u1, u2, u3);
      }
    }
  }
  __syncthreads();  // only barrier in the kernel

  // tile range for this wave: wv<8 -> 3 tiles, wv>=8 -> 2 tiles (32 total)
  const int t0 = (wv < 8) ? 3 * wv : 24 + 2 * (wv - 8);
  const int t1 = (wv < 8) ? t0 + 3 : t0 + 2;

  const long rowBase = (long)e * 65536 + (long)chunk * 1024;

  // per-lane LDS read bases; all per-read variation is immediate/induction
  const int baseA = g * 4096 + m * 16;  // + ks*8192 + ft*512
  const int baseW = g * 1024 + m * 16;  // + ks2*2048 (+512 for d+32 row)

#pragma unroll 1
  for (int it = t0; it < t1; ++it) {
    const long rb = rowBase + it * 32;  // this wave's 32 rows this tile

    // ---- load + convert x fragments ----
    short8 xf[4];
#pragma unroll
    for (int ks = 0; ks < 4; ++ks) {
      const float* px = x + (rb + m) * 64 + ks * 16 + g * 8;
      const float4 u0 = *reinterpret_cast<const float4*>(px);
      const float4 u1 = *reinterpret_cast<const float4*>(px + 4);
      short8 v;
      v[0] = (short)bfbits(u0.x); v[1] = (short)bfbits(u0.y);
      v[2] = (short)bfbits(u0.z); v[3] = (short)bfbits(u0.w);
      v[4] = (short)bfbits(u1.x); v[5] = (short)bfbits(u1.y);
      v[6] = (short)bfbits(u1.z); v[7] = (short)bfbits(u1.w);
      xf[ks] = v;
    }

    f32x16 o0, o1;  // out^T acc per dt half
#pragma unroll
    for (int i = 0; i < 16; ++i) { o0[i] = 0.f; o1[i] = 0.f; }

#pragma unroll 1
    for (int ft = 0; ft < 8; ++ft) {
      // GEMM1: h^T tile [32f x 32m]; a-reads lane-contiguous, addr = base+imm
      short8 a[4];
#pragma unroll
      for (int ks = 0; ks < 4; ++ks)
        a[ks] = lds_read16(w1t, baseA + ks * 8192 + ft * 512);

      f32x16 h;
#pragma unroll
      for (int i = 0; i < 16; ++i) h[i] = 0.f;
#pragma unroll
      for (int ks = 0; ks < 4; ++ks) h = MFMA(a[ks], xf[ks], h);

      // relu + pack to bf16 pairs: pk[2q+hh] covers C regs 4q..4q+3
      unsigned pk[8];
#pragma unroll
      for (int q = 0; q < 4; ++q) {
        pk[2*q]   = (unsigned)bfbits(fmaxf(h[4*q+0], 0.f)) | ((unsigned)bfbits(fmaxf(h[4*q+1], 0.f)) << 16);
        pk[2*q+1] = (unsigned)bfbits(fmaxf(h[4*q+2], 0.f)) | ((unsigned)bfbits(fmaxf(h[4*q+3], 0.f)) << 16);
      }

      // GEMM2 (exchange-free): B-fragment = lane's OWN pk quads; the
      // f-permutation in the W2 chunks makes the layouts line up.
#pragma unroll
      for (int sub = 0; sub < 2; ++sub) {
        const int ks2 = 2 * ft + sub;
        const short8 wA = lds_read16(w2t, baseW + ks2 * 2048);
        const short8 wB = lds_read16(w2t, baseW + 512 + ks2 * 2048);

        union { short8 v; unsigned u[4]; } b;
        b.u[0] = pk[4 * sub + 0];
        b.u[1] = pk[4 * sub + 1];
        b.u[2] = pk[4 * sub + 2];
        b.u[3] = pk[4 * sub + 3];

        o0 = MFMA(wA, b.v, o0);
        o1 = MFMA(wB, b.v, o1);
      }
    }

    // ---- store out^T C-frags NONTEMPORAL (native vec type): write-once data
    //      must not evict x from L3 (R18: FETCH=67MB = x evicted by stores) ----
#pragma unroll
    for (int dt = 0; dt < 2; ++dt) {
      const f32x16& acc = dt == 0 ? o0 : o1;
      float* po = out + (rb + m) * 64 + dt * 32 + g * 4;
#pragma unroll
      for (int q = 0; q < 4; ++q) {
        f32x4n s;
        s.x = acc[4*q+0]; s.y = acc[4*q+1]; s.z = acc[4*q+2]; s.w = acc[4*q+3];
        __builtin_nontemporal_store(s, reinterpret_cast<f32x4n*>(po + 8 * q));
      }
    }
  }
}

extern "C" void kernel_launch(void* const* d_in, const int* in_sizes, int n_in,
                              void* d_out, int out_size, void* d_ws, size_t ws_size,
                              hipStream_t stream) {
  const float* x  = (const float*)d_in[0];
  const float* w1 = (const float*)d_in[1];
  const float* w2 = (const float*)d_in[2];
  float* out = (float*)d_out;
  ffn_fused<<<dim3(512), dim3(768), 0, stream>>>(x, w1, w2, out);
}

// Round 21
// 62.996 us; speedup vs baseline: 1.3270x; 1.3270x over previous
//
#include <hip/hip_runtime.h>
#include <hip/hip_bf16.h>

typedef __attribute__((ext_vector_type(8))) short short8;
typedef __attribute__((ext_vector_type(16))) float f32x16;

__device__ __forceinline__ unsigned short bfbits(float f) {
  return __builtin_bit_cast(unsigned short, __float2bfloat16(f));
}

__device__ __forceinline__ short8 lds_read16(const short* p, int byteOff) {
  return *reinterpret_cast<const short8*>(reinterpret_cast<const char*>(p) + byteOff);
}

#define MFMA(a, b, c) __builtin_amdgcn_mfma_f32_32x32x16_bf16((a), (b), (c), 0, 0, 0)

// x:[524288][64] f32, w1:[8][64][256] f32, w2:[8][256][64] f32, out = x shape.
// Grid 512 x 512 threads. expert = blockIdx&7 (XCD-pinned), chunk =
// blockIdx>>3 owns 1024 rows; 8 waves x 4 tiles x 32 rows.
//
// R21 CHANGE -- depth-1 x prefetch on the lean R18 body:
// R18 (64.5us) heads every tile with 8 HBM loads + an implicit vmcnt(0)
// drain; with all waves phase-aligned post-staging, each CU's ~48KB burst
// queues at ~10B/cy -> multi-k-cycle exposed latency per tile (the "never
// drain vmcnt to 0" lesson). Prefetch tile it+1's loads right after
// converting tile it -> loads fly during the whole ft-loop. Register cost
// +32 (raw[8]) -> ~116 total: needs the 128 cap -> 512-thr blocks,
// 16 waves/CU (24->16 measured worth only ~1.7us, R11 vs R15).
// nt-stores REVERTED (R20: WRITE 131->198MB partial-line RMW, +19us).
//
// R18 (kept): exchange-free GEMM2 via f-permutation -- W2 chunk (ks2,g2)
// holds physical rows 16ks2+4g2+{0..3},16ks2+8+4g2+{0..3}; the lane's own
// pk quads ARE the B-fragment (no shfl_xor network). absmax-validated.
//
// LDS layouts (R13, conflict-free, addr = base + induction offset):
//   w1t chunk(c=ks*2+g, f):  byte c*4096 + f*16 = W1^T[f][d=8c..8c+7]
//   w2t chunk(c2=ks2*2+g,d): byte c2*1024 + d*16 (f-permuted contents)
__launch_bounds__(512, 2)
__global__ void ffn_fused(const float* __restrict__ x,
                          const float* __restrict__ w1,
                          const float* __restrict__ w2,
                          float* __restrict__ out) {
  __shared__ short w1t[4 * 2 * 256 * 8];   // 32 KB
  __shared__ short w2t[16 * 2 * 64 * 8];   // 32 KB

  const int tid  = threadIdx.x;
  const int lane = tid & 63;
  const int wv   = tid >> 6;   // wave 0..7
  const int m    = lane & 31;
  const int g    = lane >> 5;

  const int e     = blockIdx.x & 7;   // expert -> XCD pinned (weights L2-hot)
  const int chunk = blockIdx.x >> 3;  // 0..63

  const float* W1 = w1 + e * (64 * 256);
  const float* W2 = w2 + e * (256 * 64);

  const long rowBase = (long)e * 65536 + (long)chunk * 1024 + wv * 128;

  // ---- issue tile-0 x loads FIRST: latency hides under weight staging ----
  float4 raw[8];
#pragma unroll
  for (int ks = 0; ks < 4; ++ks) {
    const float* px = x + (rowBase + m) * 64 + ks * 16 + g * 8;
    raw[2 * ks]     = *reinterpret_cast<const float4*>(px);
    raw[2 * ks + 1] = *reinterpret_cast<const float4*>(px + 4);
  }

  // ---- stage W1 chunks: f = tid&255, chunks c = (tid>>8)*4 .. +3 ----
  // unroll 2 bounds in-flight staging loads (R7: full unroll spills)
  {
    const int f  = tid & 255;
    const int cb = (tid >> 8) * 4;
#pragma unroll 2
    for (int ci = 0; ci < 4; ++ci) {
      const int c  = cb + ci;     // c = ks*2+g
      const int d0 = c * 8;
      unsigned u0, u1, u2, u3;
      {
        float a0 = W1[(d0 + 0) * 256 + f], a1 = W1[(d0 + 1) * 256 + f];
        float a2 = W1[(d0 + 2) * 256 + f], a3 = W1[(d0 + 3) * 256 + f];
        float a4 = W1[(d0 + 4) * 256 + f], a5 = W1[(d0 + 5) * 256 + f];
        float a6 = W1[(d0 + 6) * 256 + f], a7 = W1[(d0 + 7) * 256 + f];
        u0 = (unsigned)bfbits(a0) | ((unsigned)bfbits(a1) << 16);
        u1 = (unsigned)bfbits(a2) | ((unsigned)bfbits(a3) << 16);
        u2 = (unsigned)bfbits(a4) | ((unsigned)bfbits(a5) << 16);
        u3 = (unsigned)bfbits(a6) | ((unsigned)bfbits(a7) << 16);
      }
      *reinterpret_cast<uint4*>(reinterpret_cast<char*>(w1t) + c * 4096 + f * 16) =
          make_uint4(u0, u1, u2, u3);
    }
  }
  // ---- stage W2 chunks (f-PERMUTED): d = tid&63, r = tid>>6 in 0..7,
  //      chunk c2 = r + 8*ci; contents rows 16ks2+4g2+{0..3},16ks2+8+4g2+{0..3} ----
  {
    const int d = tid & 63;
    const int r = tid >> 6;
#pragma unroll 2
    for (int ci = 0; ci < 4; ++ci) {
      const int c2    = r + 8 * ci;  // 0..31
      const int g2    = c2 & 1;
      const int ks2   = c2 >> 1;
      const int fbase = 16 * ks2 + 4 * g2;
      unsigned u0, u1, u2, u3;
      {
        float a0 = W2[(fbase + 0) * 64 + d], a1 = W2[(fbase + 1) * 64 + d];
        float a2 = W2[(fbase + 2) * 64 + d], a3 = W2[(fbase + 3) * 64 + d];
        float a4 = W2[(fbase + 8) * 64 + d], a5 = W2[(fbase + 9) * 64 + d];
        float a6 = W2[(fbase + 10) * 64 + d], a7 = W2[(fbase + 11) * 64 + d];
        u0 = (unsigned)bfbits(a0) | ((unsigned)bfbits(a1) << 16);
        u1 = (unsigned)bfbits(a2) | ((unsigned)bfbits(a3) << 16);
        u2 = (unsigned)bfbits(a4) | ((unsigned)bfbits(a5) << 16);
        u3 = (unsigned)bfbits(a6) | ((unsigned)bfbits(a7) << 16);
      }
      *reinterpret_cast<uint4*>(reinterpret_cast<char*>(w2t) + c2 * 1024 + d * 16) =
          make_uint4(u0, u1, u2, u3);
    }
  }
  __syncthreads();  // only barrier in the kernel

  // per-lane LDS read bases; all per-read variation is immediate/induction
  const int baseA = g * 4096 + m * 16;  // + ks*8192 + ft*512
  const int baseW = g * 1024 + m * 16;  // + ks2*2048 (+512 for d+32 row)

#pragma unroll 1
  for (int it = 0; it < 4; ++it) {
    const long rb = rowBase + it * 32;  // this wave's 32 rows this tile

    // ---- convert raw -> bf16 fragments, then immediately re-issue raw
    //      loads for tile it+1: they fly during the whole ft-loop ----
    short8 xf[4];
#pragma unroll
    for (int ks = 0; ks < 4; ++ks) {
      const float4 u0 = raw[2 * ks];
      const float4 u1 = raw[2 * ks + 1];
      short8 v;
      v[0] = (short)bfbits(u0.x); v[1] = (short)bfbits(u0.y);
      v[2] = (short)bfbits(u0.z); v[3] = (short)bfbits(u0.w);
      v[4] = (short)bfbits(u1.x); v[5] = (short)bfbits(u1.y);
      v[6] = (short)bfbits(u1.z); v[7] = (short)bfbits(u1.w);
      xf[ks] = v;
    }
    if (it < 3) {
      const long rbn = rb + 32;
#pragma unroll
      for (int ks = 0; ks < 4; ++ks) {
        const float* px = x + (rbn + m) * 64 + ks * 16 + g * 8;
        raw[2 * ks]     = *reinterpret_cast<const float4*>(px);
        raw[2 * ks + 1] = *reinterpret_cast<const float4*>(px + 4);
      }
    }

    f32x16 o0, o1;  // out^T acc per dt half
#pragma unroll
    for (int i = 0; i < 16; ++i) { o0[i] = 0.f; o1[i] = 0.f; }

#pragma unroll 1
    for (int ft = 0; ft < 8; ++ft) {
      // GEMM1: h^T tile [32f x 32m]; a-reads lane-contiguous, addr = base+imm
      short8 a[4];
#pragma unroll
      for (int ks = 0; ks < 4; ++ks)
        a[ks] = lds_read16(w1t, baseA + ks * 8192 + ft * 512);

      f32x16 h;
#pragma unroll
      for (int i = 0; i < 16; ++i) h[i] = 0.f;
#pragma unroll
      for (int ks = 0; ks < 4; ++ks) h = MFMA(a[ks], xf[ks], h);

      // relu + pack to bf16 pairs: pk[2q+hh] covers C regs 4q..4q+3
      unsigned pk[8];
#pragma unroll
      for (int q = 0; q < 4; ++q) {
        pk[2*q]   = (unsigned)bfbits(fmaxf(h[4*q+0], 0.f)) | ((unsigned)bfbits(fmaxf(h[4*q+1], 0.f)) << 16);
        pk[2*q+1] = (unsigned)bfbits(fmaxf(h[4*q+2], 0.f)) | ((unsigned)bfbits(fmaxf(h[4*q+3], 0.f)) << 16);
      }

      // GEMM2 (exchange-free): B-fragment = lane's OWN pk quads; the
      // f-permutation in the W2 chunks makes the layouts line up.
#pragma unroll
      for (int sub = 0; sub < 2; ++sub) {
        const int ks2 = 2 * ft + sub;
        const short8 wA = lds_read16(w2t, baseW + ks2 * 2048);
        const short8 wB = lds_read16(w2t, baseW + 512 + ks2 * 2048);

        union { short8 v; unsigned u[4]; } b;
        b.u[0] = pk[4 * sub + 0];
        b.u[1] = pk[4 * sub + 1];
        b.u[2] = pk[4 * sub + 2];
        b.u[3] = pk[4 * sub + 3];

        o0 = MFMA(wA, b.v, o0);
        o1 = MFMA(wB, b.v, o1);
      }
    }

    // ---- store out^T C-frags (normal stores: L2 write-combining needed,
    //      R20 measured nt -> +67MB partial-line RMW) ----
#pragma unroll
    for (int dt = 0; dt < 2; ++dt) {
      const f32x16& acc = dt == 0 ? o0 : o1;
      float* po = out + (rb + m) * 64 + dt * 32 + g * 4;
#pragma unroll
      for (int q = 0; q < 4; ++q) {
        float4 s;
        s.x = acc[4*q+0]; s.y = acc[4*q+1]; s.z = acc[4*q+2]; s.w = acc[4*q+3];
        *reinterpret_cast<float4*>(po + 8 * q) = s;  // d = dt*32 + 8q + 4g + 0..3
      }
    }
  }
}

extern "C" void kernel_launch(void* const* d_in, const int* in_sizes, int n_in,
                              void* d_out, int out_size, void* d_ws, size_t ws_size,
                              hipStream_t stream) {
  const float* x  = (const float*)d_in[0];
  const float* w1 = (const float*)d_in[1];
  const float* w2 = (const float*)d_in[2];
  float* out = (float*)d_out;
  ffn_fused<<<dim3(512), dim3(512), 0, stream>>>(x, w1, w2, out);
}

// Round 22
// 61.596 us; speedup vs baseline: 1.3571x; 1.0227x over previous
//
#include <hip/hip_runtime.h>
#include <hip/hip_bf16.h>

typedef __attribute__((ext_vector_type(8))) short short8;
typedef __attribute__((ext_vector_type(16))) float f32x16;

__device__ __forceinline__ unsigned short bfbits(float f) {
  return __builtin_bit_cast(unsigned short, __float2bfloat16(f));
}

__device__ __forceinline__ short8 lds_read16(const short* p, int byteOff) {
  return *reinterpret_cast<const short8*>(reinterpret_cast<const char*>(p) + byteOff);
}

#define MFMA(a, b, c) __builtin_amdgcn_mfma_f32_32x32x16_bf16((a), (b), (c), 0, 0, 0)

// x:[524288][64] f32, w1:[8][64][256] f32, w2:[8][256][64] f32, out = x shape.
// Grid 512 x 512 threads. expert = blockIdx&7 (XCD-pinned), chunk =
// blockIdx>>3 owns 1024 rows; 8 waves x 4 tiles x 32 rows.
//
// R22 CHANGE -- a-frag ping-pong SWP inside the rolled ft loop:
// R21 (63.0us) pipe-busy budget: DS ~20us, VALU ~15us, MFMA ~11us -- would
// be ~25us if overlapped; 63us measured => the per-ft chain (ds wait ->
// h-MFMA -> pack -> o-MFMA) serializes pipes and 4 waves/SIMD can't fill.
// R12's SWP failed by occupancy loss (no cap, 256thr: regs 52->80); here
// the (512,2)=128 cap protects occupancy and body=96 leaves 28 headroom:
// aB set = +16 -> ~112-124 <= 128. Next half-step's 4 W1 reads issue before
// this half-step's compute -> DS latency overlaps prev MFMA+VALU.
// Spill signature: FETCH >> 67MB.
//
// Kept: depth-1 x prefetch (R21, 64.5->63.0), exchange-free GEMM2 via
// f-permutation (R18), conflict-free chunked LDS (R13), XCD pinning,
// normal stores (R20: nt-stores -> partial-line RMW +67MB).
//
// LDS layouts (addr = base + induction offset):
//   w1t chunk(c=ks*2+g, f):  byte c*4096 + f*16 = W1^T[f][d=8c..8c+7]
//   w2t chunk(c2=ks2*2+g,d): byte c2*1024 + d*16 (f-permuted contents:
//     rows 16ks2+4g2+{0..3},16ks2+8+4g2+{0..3})
__launch_bounds__(512, 2)
__global__ void ffn_fused(const float* __restrict__ x,
                          const float* __restrict__ w1,
                          const float* __restrict__ w2,
                          float* __restrict__ out) {
  __shared__ short w1t[4 * 2 * 256 * 8];   // 32 KB
  __shared__ short w2t[16 * 2 * 64 * 8];   // 32 KB

  const int tid  = threadIdx.x;
  const int lane = tid & 63;
  const int wv   = tid >> 6;   // wave 0..7
  const int m    = lane & 31;
  const int g    = lane >> 5;

  const int e     = blockIdx.x & 7;   // expert -> XCD pinned (weights L2-hot)
  const int chunk = blockIdx.x >> 3;  // 0..63

  const float* W1 = w1 + e * (64 * 256);
  const float* W2 = w2 + e * (256 * 64);

  const long rowBase = (long)e * 65536 + (long)chunk * 1024 + wv * 128;

  // ---- issue tile-0 x loads FIRST: latency hides under weight staging ----
  float4 raw[8];
#pragma unroll
  for (int ks = 0; ks < 4; ++ks) {
    const float* px = x + (rowBase + m) * 64 + ks * 16 + g * 8;
    raw[2 * ks]     = *reinterpret_cast<const float4*>(px);
    raw[2 * ks + 1] = *reinterpret_cast<const float4*>(px + 4);
  }

  // ---- stage W1 chunks: f = tid&255, chunks c = (tid>>8)*4 .. +3 ----
  {
    const int f  = tid & 255;
    const int cb = (tid >> 8) * 4;
#pragma unroll 2
    for (int ci = 0; ci < 4; ++ci) {
      const int c  = cb + ci;     // c = ks*2+g
      const int d0 = c * 8;
      unsigned u0, u1, u2, u3;
      {
        float a0 = W1[(d0 + 0) * 256 + f], a1 = W1[(d0 + 1) * 256 + f];
        float a2 = W1[(d0 + 2) * 256 + f], a3 = W1[(d0 + 3) * 256 + f];
        float a4 = W1[(d0 + 4) * 256 + f], a5 = W1[(d0 + 5) * 256 + f];
        float a6 = W1[(d0 + 6) * 256 + f], a7 = W1[(d0 + 7) * 256 + f];
        u0 = (unsigned)bfbits(a0) | ((unsigned)bfbits(a1) << 16);
        u1 = (unsigned)bfbits(a2) | ((unsigned)bfbits(a3) << 16);
        u2 = (unsigned)bfbits(a4) | ((unsigned)bfbits(a5) << 16);
        u3 = (unsigned)bfbits(a6) | ((unsigned)bfbits(a7) << 16);
      }
      *reinterpret_cast<uint4*>(reinterpret_cast<char*>(w1t) + c * 4096 + f * 16) =
          make_uint4(u0, u1, u2, u3);
    }
  }
  // ---- stage W2 chunks (f-PERMUTED): d = tid&63, r = tid>>6 in 0..7 ----
  {
    const int d = tid & 63;
    const int r = tid >> 6;
#pragma unroll 2
    for (int ci = 0; ci < 4; ++ci) {
      const int c2    = r + 8 * ci;  // 0..31
      const int g2    = c2 & 1;
      const int ks2   = c2 >> 1;
      const int fbase = 16 * ks2 + 4 * g2;
      unsigned u0, u1, u2, u3;
      {
        float a0 = W2[(fbase + 0) * 64 + d], a1 = W2[(fbase + 1) * 64 + d];
        float a2 = W2[(fbase + 2) * 64 + d], a3 = W2[(fbase + 3) * 64 + d];
        float a4 = W2[(fbase + 8) * 64 + d], a5 = W2[(fbase + 9) * 64 + d];
        float a6 = W2[(fbase + 10) * 64 + d], a7 = W2[(fbase + 11) * 64 + d];
        u0 = (unsigned)bfbits(a0) | ((unsigned)bfbits(a1) << 16);
        u1 = (unsigned)bfbits(a2) | ((unsigned)bfbits(a3) << 16);
        u2 = (unsigned)bfbits(a4) | ((unsigned)bfbits(a5) << 16);
        u3 = (unsigned)bfbits(a6) | ((unsigned)bfbits(a7) << 16);
      }
      *reinterpret_cast<uint4*>(reinterpret_cast<char*>(w2t) + c2 * 1024 + d * 16) =
          make_uint4(u0, u1, u2, u3);
    }
  }
  __syncthreads();  // only barrier in the kernel

  // per-lane LDS read bases; all per-read variation is immediate/induction
  const int baseA = g * 4096 + m * 16;  // + ks*8192 + ft*512
  const int baseW = g * 1024 + m * 16;  // + ks2*2048 (+512 for d+32 row)

// one ft half-step on a given a-frag set (exchange-free GEMM2)
#define FT_STEP(AA, FT)                                                         \
  {                                                                             \
    f32x16 h;                                                                   \
    _Pragma("unroll")                                                           \
    for (int i = 0; i < 16; ++i) h[i] = 0.f;                                    \
    _Pragma("unroll")                                                           \
    for (int ks = 0; ks < 4; ++ks) h = MFMA(AA[ks], xf[ks], h);                 \
    unsigned pk[8];                                                             \
    _Pragma("unroll")                                                           \
    for (int q = 0; q < 4; ++q) {                                               \
      pk[2*q]   = (unsigned)bfbits(fmaxf(h[4*q+0], 0.f)) |                      \
                  ((unsigned)bfbits(fmaxf(h[4*q+1], 0.f)) << 16);               \
      pk[2*q+1] = (unsigned)bfbits(fmaxf(h[4*q+2], 0.f)) |                      \
                  ((unsigned)bfbits(fmaxf(h[4*q+3], 0.f)) << 16);               \
    }                                                                           \
    _Pragma("unroll")                                                           \
    for (int sub = 0; sub < 2; ++sub) {                                         \
      const int ks2 = 2 * (FT) + sub;                                           \
      const short8 wA = lds_read16(w2t, baseW + ks2 * 2048);                    \
      const short8 wB = lds_read16(w2t, baseW + 512 + ks2 * 2048);              \
      union { short8 v; unsigned u[4]; } b;                                     \
      b.u[0] = pk[4 * sub + 0];                                                 \
      b.u[1] = pk[4 * sub + 1];                                                 \
      b.u[2] = pk[4 * sub + 2];                                                 \
      b.u[3] = pk[4 * sub + 3];                                                 \
      o0 = MFMA(wA, b.v, o0);                                                   \
      o1 = MFMA(wB, b.v, o1);                                                   \
    }                                                                           \
  }

#define LOAD_A(DST, FT)                                                         \
  _Pragma("unroll")                                                             \
  for (int ks = 0; ks < 4; ++ks)                                                \
    DST[ks] = lds_read16(w1t, baseA + ks * 8192 + (FT) * 512);

#pragma unroll 1
  for (int it = 0; it < 4; ++it) {
    const long rb = rowBase + it * 32;  // this wave's 32 rows this tile

    // ---- convert raw -> xf, then re-issue raw for tile it+1 ----
    short8 xf[4];
#pragma unroll
    for (int ks = 0; ks < 4; ++ks) {
      const float4 u0 = raw[2 * ks];
      const float4 u1 = raw[2 * ks + 1];
      short8 v;
      v[0] = (short)bfbits(u0.x); v[1] = (short)bfbits(u0.y);
      v[2] = (short)bfbits(u0.z); v[3] = (short)bfbits(u0.w);
      v[4] = (short)bfbits(u1.x); v[5] = (short)bfbits(u1.y);
      v[6] = (short)bfbits(u1.z); v[7] = (short)bfbits(u1.w);
      xf[ks] = v;
    }
    if (it < 3) {
      const long rbn = rb + 32;
#pragma unroll
      for (int ks = 0; ks < 4; ++ks) {
        const float* px = x + (rbn + m) * 64 + ks * 16 + g * 8;
        raw[2 * ks]     = *reinterpret_cast<const float4*>(px);
        raw[2 * ks + 1] = *reinterpret_cast<const float4*>(px + 4);
      }
    }

    f32x16 o0, o1;  // out^T acc per dt half
#pragma unroll
    for (int i = 0; i < 16; ++i) { o0[i] = 0.f; o1[i] = 0.f; }

    // ---- ft ping-pong: issue next half-step's a-reads before compute ----
    short8 aA[4], aB[4];
    LOAD_A(aA, 0)
#pragma unroll 1
    for (int ftp = 0; ftp < 4; ++ftp) {
      const int ft0 = 2 * ftp;
      LOAD_A(aB, ft0 + 1)          // fly under FT_STEP(aA)
      FT_STEP(aA, ft0)
      LOAD_A(aA, (ft0 + 2) & 7)    // fly under FT_STEP(aB); &7: tail re-read
      FT_STEP(aB, ft0 + 1)
    }

    // ---- store out^T C-frags ----
#pragma unroll
    for (int dt = 0; dt < 2; ++dt) {
      const f32x16& acc = dt == 0 ? o0 : o1;
      float* po = out + (rb + m) * 64 + dt * 32 + g * 4;
#pragma unroll
      for (int q = 0; q < 4; ++q) {
        float4 s;
        s.x = acc[4*q+0]; s.y = acc[4*q+1]; s.z = acc[4*q+2]; s.w = acc[4*q+3];
        *reinterpret_cast<float4*>(po + 8 * q) = s;  // d = dt*32 + 8q + 4g + 0..3
      }
    }
  }
#undef FT_STEP
#undef LOAD_A
}

extern "C" void kernel_launch(void* const* d_in, const int* in_sizes, int n_in,
                              void* d_out, int out_size, void* d_ws, size_t ws_size,
                              hipStream_t stream) {
  const float* x  = (const float*)d_in[0];
  const float* w1 = (const float*)d_in[1];
  const float* w2 = (const float*)d_in[2];
  float* out = (float*)d_out;
  ffn_fused<<<dim3(512), dim3(512), 0, stream>>>(x, w1, w2, out);
}